// Round 17
// baseline (152.312 us; speedup 1.0000x reference)
//
#include <hip/hip_runtime.h>
#include <hip/hip_bf16.h>
#include <math.h>

#define NB 8192
#define DD 512
#define HH 256
#define TB 128             // sim tile 128x128
#define BK 32              // mlp gemm k-tile
#define BK2 64             // sim k-tile
#define KT2 (DD / BK2)     // 8 k-steps in sim
#define NSLOT 64
#define ROWKEYS (NSLOT * 3)
#define NCAND 6
#define NTRI 2080          // 64*65/2

typedef unsigned short ushortT;
typedef __attribute__((ext_vector_type(8))) short bf16x8;
typedef __attribute__((ext_vector_type(4))) float f32x4;

#define AS1(p) ((const __attribute__((address_space(1))) void*)(p))
#define AS3(p) ((__attribute__((address_space(3))) void*)(p))

__device__ __forceinline__ ushortT bf16rne(float f) {
    unsigned u = __float_as_uint(f);
    unsigned r = u + 0x7FFFu + ((u >> 16) & 1u);
    return (ushortT)(r >> 16);
}
__device__ __forceinline__ float bf16tof(ushortT h) {
    return __uint_as_float(((unsigned)h) << 16);
}

// ---------------- Kernel 0: prep ----------------
__global__ __launch_bounds__(256)
void prep_kernel(const float* __restrict__ sess, const float* __restrict__ W1,
                 const float* __restrict__ W2,
                 ushortT* __restrict__ sess_hi, ushortT* __restrict__ sess_lo,
                 ushortT* __restrict__ w1t_hi, ushortT* __restrict__ w1t_lo,
                 ushortT* __restrict__ w2t_hi, ushortT* __restrict__ w2t_lo) {
    const int b = blockIdx.x, t = threadIdx.x;
    if (b < 2048) {
        size_t i = (size_t)b * 2048 + t * 8;
        float4 f0 = *(const float4*)&sess[i];
        float4 f1 = *(const float4*)&sess[i + 4];
        float f[8] = {f0.x, f0.y, f0.z, f0.w, f1.x, f1.y, f1.z, f1.w};
        unsigned hp[4], lp[4];
#pragma unroll
        for (int j = 0; j < 4; ++j) {
            ushortT h0 = bf16rne(f[2 * j]), h1 = bf16rne(f[2 * j + 1]);
            ushortT l0 = bf16rne(f[2 * j] - bf16tof(h0));
            ushortT l1 = bf16rne(f[2 * j + 1] - bf16tof(h1));
            hp[j] = (unsigned)h0 | ((unsigned)h1 << 16);
            lp[j] = (unsigned)l0 | ((unsigned)l1 << 16);
        }
        *(uint4*)&sess_hi[i] = *(uint4*)hp;
        *(uint4*)&sess_lo[i] = *(uint4*)lp;
    } else if (b < 2112) {
        int o = (b - 2048) * 2048 + t * 8;
        int k = o >> 8, c = o & 255;
        float4 f0 = *(const float4*)&W1[(size_t)k * 256 + c];
        float4 f1 = *(const float4*)&W1[(size_t)k * 256 + c + 4];
        float f[8] = {f0.x, f0.y, f0.z, f0.w, f1.x, f1.y, f1.z, f1.w};
#pragma unroll
        for (int j = 0; j < 8; ++j) {
            ushortT h = bf16rne(f[j]);
            w1t_hi[(size_t)(c + j) * 512 + k] = h;
            w1t_lo[(size_t)(c + j) * 512 + k] = bf16rne(f[j] - bf16tof(h));
        }
    } else {
        int o = (b - 2112) * 2048 + t * 8;
        int k = o >> 9, c = o & 511;
        float4 f0 = *(const float4*)&W2[(size_t)k * 512 + c];
        float4 f1 = *(const float4*)&W2[(size_t)k * 512 + c + 4];
        float f[8] = {f0.x, f0.y, f0.z, f0.w, f1.x, f1.y, f1.z, f1.w};
#pragma unroll
        for (int j = 0; j < 8; ++j) {
            ushortT h = bf16rne(f[j]);
            w2t_hi[(size_t)(c + j) * 256 + k] = h;
            w2t_lo[(size_t)(c + j) * 256 + k] = bf16rne(f[j] - bf16tof(h));
        }
    }
}

// -------- Kernel 1/2: split-bf16 MFMA GEMM, C = A @ B^T (+bias), TM x 128 tile --------
template <int KDIM, int NOUT, int EPI, int TM>
__global__ __launch_bounds__(256)
void mlp_gemm(const ushortT* __restrict__ Ahi, const ushortT* __restrict__ Alo,
              const ushortT* __restrict__ Bhi, const ushortT* __restrict__ Blo,
              const float* __restrict__ bias,
              ushortT* __restrict__ Ohi, ushortT* __restrict__ Olo,
              float* __restrict__ Of, ushortT* __restrict__ Ob) {
    constexpr int AC = TM / 16;
    constexpr int BC = 8;
    constexpr int CHUNKS = 2 * AC + 2 * BC;
    constexpr int QN = CHUNKS / 4;
    constexpr int BUFS = CHUNKS * 512;
    constexpr int MI = TM / 32;
    constexpr int NJ = 4;
    __shared__ short gsmem[2 * BUFS];
    const int KTILES = KDIM / BK;
    const int t = threadIdx.x;
    const int w = t >> 6, l = t & 63;
    const int wr = w >> 1, wc = w & 1;
    const int tx = l & 15, tg = l >> 4;
    const int rb = blockIdx.x * TM;
    const int cb = blockIdx.y * 128;

    const int rin = l >> 2;
    const int tgs = (l & 3) ^ ((rin >> 1) & 3);
    const int loff = tx * BK + ((tg ^ ((tx >> 1) & 3)) << 3);

    f32x4 acc[MI][NJ];
#pragma unroll
    for (int i = 0; i < MI; ++i)
#pragma unroll
        for (int j = 0; j < NJ; ++j) acc[i][j] = (f32x4){0.f, 0.f, 0.f, 0.f};

#define GSTAGE(buf, k0v)                                                                     \
    {                                                                                        \
        _Pragma("unroll")                                                                    \
        for (int q = 0; q < QN; ++q) {                                                       \
            int c = w * QN + q;                                                              \
            const ushortT* src; int row; int lofs;                                           \
            if (c < AC)              { src = Ahi; row = rb + c * 16 + rin;                lofs = c * 512; } \
            else if (c < 2 * AC)     { src = Alo; row = rb + (c - AC) * 16 + rin;         lofs = c * 512; } \
            else if (c < 2 * AC + BC){ src = Bhi; row = cb + (c - 2 * AC) * 16 + rin;     lofs = c * 512; } \
            else                     { src = Blo; row = cb + (c - 2 * AC - BC) * 16 + rin; lofs = c * 512; } \
            const ushortT* g = src + (size_t)row * KDIM + (k0v) + tgs * 8;                   \
            __builtin_amdgcn_global_load_lds(AS1(g), AS3(gsmem + (buf) * BUFS + lofs + l * 8), 16, 0, 0); \
        }                                                                                    \
    }

#define GCOMPUTE(kt)                                                                         \
    {                                                                                        \
        const short* Bu = gsmem + ((kt) & 1) * BUFS;                                         \
        bf16x8 ah[MI], al[MI], bh[NJ], bl[NJ];                                               \
        _Pragma("unroll")                                                                    \
        for (int mi = 0; mi < MI; ++mi) {                                                    \
            ah[mi] = *(const bf16x8*)&Bu[(wr * MI + mi) * 512 + loff];                       \
            al[mi] = *(const bf16x8*)&Bu[AC * 512 + (wr * MI + mi) * 512 + loff];            \
        }                                                                                    \
        _Pragma("unroll")                                                                    \
        for (int nj = 0; nj < NJ; ++nj) {                                                    \
            bh[nj] = *(const bf16x8*)&Bu[2 * AC * 512 + (wc * NJ + nj) * 512 + loff];        \
            bl[nj] = *(const bf16x8*)&Bu[(2 * AC + BC) * 512 + (wc * NJ + nj) * 512 + loff]; \
        }                                                                                    \
        asm volatile("s_waitcnt lgkmcnt(0)" ::: "memory");                                   \
        __builtin_amdgcn_sched_barrier(0);                                                   \
        __builtin_amdgcn_s_barrier();                                                        \
        __builtin_amdgcn_sched_barrier(0);                                                   \
        _Pragma("unroll")                                                                    \
        for (int mi = 0; mi < MI; ++mi)                                                      \
            _Pragma("unroll")                                                                \
            for (int nj = 0; nj < NJ; ++nj) {                                                \
                acc[mi][nj] = __builtin_amdgcn_mfma_f32_16x16x32_bf16(ah[mi], bh[nj], acc[mi][nj], 0, 0, 0); \
                acc[mi][nj] = __builtin_amdgcn_mfma_f32_16x16x32_bf16(ah[mi], bl[nj], acc[mi][nj], 0, 0, 0); \
                acc[mi][nj] = __builtin_amdgcn_mfma_f32_16x16x32_bf16(al[mi], bh[nj], acc[mi][nj], 0, 0, 0); \
            }                                                                                \
    }

    GSTAGE(0, 0);
    for (int kt = 0; kt < KTILES - 1; ++kt) {
        GSTAGE((kt + 1) & 1, (kt + 1) * BK);
        if constexpr (TM == 64) { asm volatile("s_waitcnt vmcnt(6)" ::: "memory"); }
        else                    { asm volatile("s_waitcnt vmcnt(5)" ::: "memory"); }
        __builtin_amdgcn_sched_barrier(0);
        __builtin_amdgcn_s_barrier();
        __builtin_amdgcn_sched_barrier(0);
        GCOMPUTE(kt);
    }
    asm volatile("s_waitcnt vmcnt(0)" ::: "memory");
    __builtin_amdgcn_sched_barrier(0);
    __builtin_amdgcn_s_barrier();
    __builtin_amdgcn_sched_barrier(0);
    GCOMPUTE(KTILES - 1);
#undef GSTAGE
#undef GCOMPUTE

#pragma unroll
    for (int mi = 0; mi < MI; ++mi) {
#pragma unroll
        for (int nj = 0; nj < NJ; ++nj) {
            int col = cb + wc * 64 + nj * 16 + tx;
            float bv = bias[col];
#pragma unroll
            for (int rr = 0; rr < 4; ++rr) {
                int row = rb + wr * (TM / 2) + mi * 16 + tg * 4 + rr;
                float v = acc[mi][nj][rr] + bv;
                if (EPI == 0) {
                    v = fmaxf(v, 0.f);
                    ushortT h = bf16rne(v);
                    Ohi[(size_t)row * NOUT + col] = h;
                    Olo[(size_t)row * NOUT + col] = bf16rne(v - bf16tof(h));
                } else {
                    Of[(size_t)row * NOUT + col] = v;
                    Ob[(size_t)row * NOUT + col] = bf16rne(v);
                }
            }
        }
    }
}

// ---- packed-key top-3 helpers (keys unique: index embedded -> any exact network OK) ----
__device__ __forceinline__ unsigned umaxu(unsigned a, unsigned b) { return a > b ? a : b; }
__device__ __forceinline__ unsigned uminu(unsigned a, unsigned b) { return a < b ? a : b; }
__device__ __forceinline__ void merge3k(unsigned& a0, unsigned& a1, unsigned& a2,
                                        unsigned b0, unsigned b1, unsigned b2) {
    unsigned m0 = a0 > b0 ? a0 : b0;
    bool c0 = a0 > b0;
    unsigned ca1 = c0 ? a1 : b1;
    unsigned cb0 = c0 ? b0 : a0;
    unsigned ca2 = c0 ? a2 : b2;
    unsigned cb1 = c0 ? b1 : a1;
    bool c1 = ca1 > cb0;
    unsigned m1 = c1 ? ca1 : cb0;
    unsigned x = c1 ? ca2 : ca1;
    unsigned y = c1 ? cb0 : cb1;
    unsigned m2 = x > y ? x : y;
    a0 = m0; a1 = m1; a2 = m2;
}
// exact top-3 of 4 distinct keys
__device__ __forceinline__ void top3of4(unsigned a, unsigned b, unsigned c, unsigned d,
                                        unsigned& k0, unsigned& k1, unsigned& k2) {
    unsigned s1 = umaxu(a, b), t1 = uminu(a, b);
    unsigned s2 = umaxu(c, d), t2 = uminu(c, d);
    bool cw = s1 > s2;
    unsigned c2 = cw ? s2 : s1;
    unsigned tw = cw ? t1 : t2;
    unsigned tl = cw ? t2 : t1;
    k0 = cw ? s1 : s2;
    k1 = umaxu(c2, tw);
    k2 = umaxu(uminu(c2, tw), tl);
}
__device__ __forceinline__ unsigned packkey(float f, unsigned idx) {
    unsigned u = __float_as_uint(f);
    unsigned tt = (unsigned)((int)u >> 31) | 0x80000000u;
    return ((u ^ tt) & 0xFFFFE000u) | (8191u - idx);
}

// ------- Kernel 3: symmetric bf16 MFMA sim, 128x128 tiles, BK=64, 512 threads (8 waves) -------
// 8 waves (2 wr x 4 wc) -> per-wave C = 64x32 (acc 4x2), 4 staging loads/thread, vmcnt(4).
// Doubles waves/SIMD to hide per-step vmcnt/L2 stalls. Same ascending-k chains -> identical keys.
__global__ __launch_bounds__(512)
void sim_mfma_kernel(const short* __restrict__ projb, unsigned* __restrict__ pkeys) {
    const int b = blockIdx.x;
    const int L = (b & 7) * 260 + (b >> 3);
    int jbk = (int)((sqrtf(8.0f * L + 1.0f) - 1.0f) * 0.5f);
    while ((jbk + 1) * (jbk + 2) / 2 <= L) ++jbk;
    while (jbk * (jbk + 1) / 2 > L) --jbk;
    const int ib = L - jbk * (jbk + 1) / 2;
    const bool do_tr = (ib < jbk);

    __shared__ short smem[2 * TB * BK2 * 2];   // 64 KB: As[2][128*64], Bs[2][128*64]
    short* As = smem;
    short* Bs = smem + 2 * TB * BK2;
    unsigned* evu = (unsigned*)smem;           // epilogue overlay [128][12]
    unsigned* evt = (unsigned*)smem + 1536;    // transposed overlay [128][6]

    const int t = threadIdx.x;
    const int wid = t >> 6, l = t & 63;
    const int wr = wid >> 2, wc = wid & 3;     // 2 x 4 wave grid
    const int tx = l & 15, tg = l >> 4;
    const int rb = ib * TB;
    const int jb = jbk * TB;

    const int sl8 = (((l & 7) ^ (l >> 3)) << 3);
    const int sw0 = (((0 + tg) ^ (tx & 7)) << 3);
    const int sw1 = (((4 + tg) ^ (tx & 7)) << 3);

    f32x4 acc[4][2];
#pragma unroll
    for (int i = 0; i < 4; ++i)
#pragma unroll
        for (int j = 0; j < 2; ++j) acc[i][j] = (f32x4){0.f, 0.f, 0.f, 0.f};

    // 16 chunks of 1KB per matrix; chunk c served by wave wid for q in {0,1}: 4 loads/thread
#define STAGE(buf, k0)                                                                      \
    {                                                                                       \
        _Pragma("unroll")                                                                   \
        for (int q = 0; q < 2; ++q) {                                                       \
            int c = wid * 2 + q;                                                            \
            const short* ga = projb + (size_t)(rb + c * 8 + (l >> 3)) * DD + (k0) + sl8;    \
            __builtin_amdgcn_global_load_lds(AS1(ga), AS3(As + (buf) * 8192 + c * 512 + l * 8), 16, 0, 0); \
            const short* gb = projb + (size_t)(jb + c * 8 + (l >> 3)) * DD + (k0) + sl8;    \
            __builtin_amdgcn_global_load_lds(AS1(gb), AS3(Bs + (buf) * 8192 + c * 512 + l * 8), 16, 0, 0); \
        }                                                                                   \
    }

#define COMPUTE(kt)                                                                          \
    {                                                                                        \
        const short* Ab = As + ((kt) & 1) * 8192;                                            \
        const short* Bb = Bs + ((kt) & 1) * 8192;                                            \
        bf16x8 af0[4], af1[4], bf0[2], bf1[2];                                               \
        _Pragma("unroll")                                                                    \
        for (int mi = 0; mi < 4; ++mi) {                                                     \
            int row = wr * 64 + mi * 16 + tx;                                                \
            af0[mi] = *(const bf16x8*)&Ab[row * 64 + sw0];                                   \
            af1[mi] = *(const bf16x8*)&Ab[row * 64 + sw1];                                   \
        }                                                                                    \
        _Pragma("unroll")                                                                    \
        for (int nj = 0; nj < 2; ++nj) {                                                     \
            int row = wc * 32 + nj * 16 + tx;                                                \
            bf0[nj] = *(const bf16x8*)&Bb[row * 64 + sw0];                                   \
            bf1[nj] = *(const bf16x8*)&Bb[row * 64 + sw1];                                   \
        }                                                                                    \
        asm volatile("s_waitcnt lgkmcnt(0)" ::: "memory");                                   \
        __builtin_amdgcn_sched_barrier(0);                                                   \
        __builtin_amdgcn_s_barrier();                                                        \
        __builtin_amdgcn_sched_barrier(0);                                                   \
        _Pragma("unroll")                                                                    \
        for (int mi = 0; mi < 4; ++mi)                                                       \
            _Pragma("unroll")                                                                \
            for (int nj = 0; nj < 2; ++nj)                                                   \
                acc[mi][nj] = __builtin_amdgcn_mfma_f32_16x16x32_bf16(af0[mi], bf0[nj], acc[mi][nj], 0, 0, 0); \
        _Pragma("unroll")                                                                    \
        for (int mi = 0; mi < 4; ++mi)                                                       \
            _Pragma("unroll")                                                                \
            for (int nj = 0; nj < 2; ++nj)                                                   \
                acc[mi][nj] = __builtin_amdgcn_mfma_f32_16x16x32_bf16(af1[mi], bf1[nj], acc[mi][nj], 0, 0, 0); \
    }

    STAGE(0, 0);
    for (int kt = 0; kt < KT2 - 1; ++kt) {
        STAGE((kt + 1) & 1, (kt + 1) * BK2);
        asm volatile("s_waitcnt vmcnt(4)" ::: "memory");
        __builtin_amdgcn_sched_barrier(0);
        __builtin_amdgcn_s_barrier();
        __builtin_amdgcn_sched_barrier(0);
        COMPUTE(kt);
    }
    asm volatile("s_waitcnt vmcnt(0)" ::: "memory");
    __builtin_amdgcn_sched_barrier(0);
    __builtin_amdgcn_s_barrier();
    __builtin_amdgcn_sched_barrier(0);
    COMPUTE(KT2 - 1);
#undef STAGE
#undef COMPUTE

    __syncthreads();   // K-loop done everywhere before LDS overlay

    // ---- direct epilogue: per-row top3 over this block's 128 cols ----
    unsigned cinv[2];
#pragma unroll
    for (int nj = 0; nj < 2; ++nj)
        cinv[nj] = 8191u - (unsigned)(jb + wc * 32 + nj * 16 + tx);
#pragma unroll
    for (int mi = 0; mi < 4; ++mi) {
#pragma unroll
        for (int rr = 0; rr < 4; ++rr) {
            unsigned ka, kb;
            {
                unsigned u0 = __float_as_uint(acc[mi][0][rr]);
                unsigned t0 = (unsigned)((int)u0 >> 31) | 0x80000000u;
                unsigned u1 = __float_as_uint(acc[mi][1][rr]);
                unsigned t1 = (unsigned)((int)u1 >> 31) | 0x80000000u;
                ka = ((u0 ^ t0) & 0xFFFFE000u) | cinv[0];
                kb = ((u1 ^ t1) & 0xFFFFE000u) | cinv[1];
            }
            unsigned k0 = umaxu(ka, kb), k1 = uminu(ka, kb), k2 = 0;
            // butterfly over all 16 tx lanes (stays within tg group for s<16)
#pragma unroll
            for (int s = 1; s <= 8; s <<= 1) {
                unsigned b0 = (unsigned)__shfl_xor((int)k0, s, 64);
                unsigned b1 = (unsigned)__shfl_xor((int)k1, s, 64);
                unsigned b2 = (unsigned)__shfl_xor((int)k2, s, 64);
                merge3k(k0, k1, k2, b0, b1, b2);
            }
            if (tx == 0) {
                int lrow = wr * 64 + mi * 16 + tg * 4 + rr;
                unsigned* e = &evu[lrow * 12 + wc * 3];
                e[0] = k0; e[1] = k1; e[2] = k2;
            }
        }
    }

    // ---- transposed epilogue (strictly-upper): per-col top3 over this block's 128 rows ----
    if (do_tr) {
#pragma unroll
        for (int nj = 0; nj < 2; ++nj) {
            unsigned v[16];
#pragma unroll
            for (int mi = 0; mi < 4; ++mi)
#pragma unroll
                for (int rr = 0; rr < 4; ++rr) {
                    unsigned idx = (unsigned)(rb + wr * 64 + mi * 16 + tg * 4 + rr);
                    v[mi * 4 + rr] = packkey(acc[mi][nj][rr], idx);
                }
            unsigned x0, x1, x2, y0, y1, y2, z0, z1, z2;
            top3of4(v[0], v[1], v[2], v[3], x0, x1, x2);
            top3of4(v[4], v[5], v[6], v[7], y0, y1, y2);
            merge3k(x0, x1, x2, y0, y1, y2);
            top3of4(v[8], v[9], v[10], v[11], y0, y1, y2);
            top3of4(v[12], v[13], v[14], v[15], z0, z1, z2);
            merge3k(y0, y1, y2, z0, z1, z2);
            merge3k(x0, x1, x2, y0, y1, y2);
#pragma unroll
            for (int s = 16; s <= 32; s <<= 1) {
                unsigned b0 = (unsigned)__shfl_xor((int)x0, s, 64);
                unsigned b1 = (unsigned)__shfl_xor((int)x1, s, 64);
                unsigned b2 = (unsigned)__shfl_xor((int)x2, s, 64);
                merge3k(x0, x1, x2, b0, b1, b2);
            }
            if (tg == 0) {
                int col = wc * 32 + nj * 16 + tx;
                unsigned* e = &evt[col * 6 + wr * 3];
                e[0] = x0; e[1] = x1; e[2] = x2;
            }
        }
    }
    __syncthreads();

    if (t < TB) {
        const unsigned* e = &evu[t * 12];
        unsigned k0 = e[0], k1 = e[1], k2 = e[2];
#pragma unroll
        for (int s = 1; s < 4; ++s) merge3k(k0, k1, k2, e[s * 3], e[s * 3 + 1], e[s * 3 + 2]);
        unsigned* pk = pkeys + (size_t)(rb + t) * ROWKEYS + jbk * 3;
        pk[0] = k0; pk[1] = k1; pk[2] = k2;
    }
    if (do_tr && t < TB) {
        const unsigned* e = &evt[t * 6];
        unsigned k0 = e[0], k1 = e[1], k2 = e[2];
        merge3k(k0, k1, k2, e[3], e[4], e[5]);
        unsigned* pk = pkeys + (size_t)(jb + t) * ROWKEYS + ib * 3;
        pk[0] = k0; pk[1] = k1; pk[2] = k2;
    }
}

// --- Kernel 4: parallel top-6 of 192 keys + exact fp64 re-rank + softmax + gather + out ---
__global__ __launch_bounds__(256)
void rerank_out_kernel(const float* __restrict__ proj, const unsigned* __restrict__ pkeys,
                       const float* __restrict__ sess, float* __restrict__ out,
                       float* __restrict__ cos_out) {
    int r = blockIdx.x * 4 + (threadIdx.x >> 6);
    int t = threadIdx.x & 63;
    const unsigned* pk = pkeys + (size_t)r * ROWKEYS;
    unsigned a0 = pk[3 * t], a1 = pk[3 * t + 1], a2 = pk[3 * t + 2];
    {
        unsigned m01 = a0 > a1 ? a0 : a1, n01 = a0 > a1 ? a1 : a0;
        unsigned m2 = n01 > a2 ? n01 : a2, n2 = n01 > a2 ? a2 : n01;
        a0 = m01 > m2 ? m01 : m2;
        a1 = m01 > m2 ? m2 : m01;
        a2 = n2;
    }
    unsigned ck[NCAND];
#pragma unroll
    for (int i = 0; i < NCAND; ++i) {
        unsigned m = a0;
#pragma unroll
        for (int s = 1; s < 64; s <<= 1) {
            unsigned o = (unsigned)__shfl_xor((int)m, s, 64);
            m = m > o ? m : o;
        }
        ck[i] = m;
        if (a0 == m) { a0 = a1; a1 = a2; a2 = 0; }
    }
    int cj[NCAND];
#pragma unroll
    for (int i = 0; i < NCAND; ++i) cj[i] = 8191 - (int)(ck[i] & 0x1FFFu);

    const float* pr = proj + (size_t)r * DD;
    float myp[8];
#pragma unroll
    for (int k = 0; k < 8; ++k) myp[k] = pr[t * 8 + k];
    double part[NCAND];
#pragma unroll
    for (int i = 0; i < NCAND; ++i) {
        const float* pc = proj + (size_t)cj[i] * DD;
        double s = 0.0;
#pragma unroll
        for (int k = 0; k < 8; ++k) s += (double)myp[k] * (double)pc[t * 8 + k];
        part[i] = s;
    }
#pragma unroll
    for (int i = 0; i < NCAND; ++i) {
#pragma unroll
        for (int s = 1; s < 64; s <<= 1) part[i] += __shfl_xor(part[i], s, 64);
    }
    double bv0 = -1e300, bv1 = -1e300, bv2 = -1e300;
    int bj0 = 0x7fffffff, bj1 = 0x7fffffff, bj2 = 0x7fffffff;
#pragma unroll
    for (int i = 0; i < NCAND; ++i) {
        double v = part[i]; int j = cj[i];
        bool g2 = (v > bv2) || (v == bv2 && j < bj2);
        bool g1 = (v > bv1) || (v == bv1 && j < bj1);
        bool g0 = (v > bv0) || (v == bv0 && j < bj0);
        if (g2) {
            if (g1) {
                if (g0) { bv2 = bv1; bj2 = bj1; bv1 = bv0; bj1 = bj0; bv0 = v; bj0 = j; }
                else    { bv2 = bv1; bj2 = bj1; bv1 = v; bj1 = j; }
            } else      { bv2 = v; bj2 = j; }
        }
    }
    double e1 = exp(bv1 - bv0), e2 = exp(bv2 - bv0);
    double inv = 1.0 / (1.0 + e1 + e2);
    float w0 = (float)inv, w1 = (float)(e1 * inv), w2 = (float)(e2 * inv);
    if (t == 0) {
        cos_out[r * 3 + 0] = w0; cos_out[r * 3 + 1] = w1; cos_out[r * 3 + 2] = w2;
    }
    const float4* s0 = (const float4*)(sess + (size_t)bj0 * DD);
    const float4* s1 = (const float4*)(sess + (size_t)bj1 * DD);
    const float4* s2 = (const float4*)(sess + (size_t)bj2 * DD);
    float4* o = (float4*)(out + (size_t)r * 3 * DD);
    float4* nb = (float4*)(out + (size_t)NB * 3 * DD + (size_t)r * DD);
#pragma unroll
    for (int e = 0; e < 2; ++e) {
        int q = t + e * 64;
        float4 x0 = s0[q], x1 = s1[q], x2 = s2[q];
        o[q] = x0; o[128 + q] = x1; o[256 + q] = x2;
        float4 v;
        v.x = fmaf(w0, x0.x, fmaf(w1, x1.x, w2 * x2.x));
        v.y = fmaf(w0, x0.y, fmaf(w1, x1.y, w2 * x2.y));
        v.z = fmaf(w0, x0.z, fmaf(w1, x1.z, w2 * x2.z));
        v.w = fmaf(w0, x0.w, fmaf(w1, x1.w, w2 * x2.w));
        nb[q] = v;
    }
}

extern "C" void kernel_launch(void* const* d_in, const int* in_sizes, int n_in,
                              void* d_out, int out_size, void* d_ws, size_t ws_size,
                              hipStream_t stream) {
    const float* sess = (const float*)d_in[0];
    // d_in[1] = pool_emb: unused by the reference
    const float* W1 = (const float*)d_in[2];
    const float* b1 = (const float*)d_in[3];
    const float* W2 = (const float*)d_in[4];
    const float* b2 = (const float*)d_in[5];
    float* out = (float*)d_out;

    const size_t MBc = 1u << 20;
    char* W = (char*)d_ws;
    float*   proj    = (float*)W;
    ushortT* sess_hi = (ushortT*)W;
    ushortT* sess_lo = sess_hi + (size_t)NB * DD;
    ushortT* projb   = (ushortT*)(W + 16 * MBc);
    ushortT* h_hi    = (ushortT*)(W + 24 * MBc);
    ushortT* h_lo    = (ushortT*)(W + 28 * MBc);
    ushortT* w1t_hi  = (ushortT*)(W + 32 * MBc);
    ushortT* w1t_lo  = w1t_hi + 256 * 512;
    ushortT* w2t_hi  = w1t_lo + 256 * 512;
    ushortT* w2t_lo  = w2t_hi + 512 * 256;
    unsigned* pkeys  = (unsigned*)(W + 24 * MBc);   // overlays h_hi/h_lo after gemm2

    float* cos_out = out + (size_t)NB * 3 * DD + (size_t)NB * DD;

    hipLaunchKernelGGL(prep_kernel, dim3(2176), dim3(256), 0, stream,
                       sess, W1, W2, sess_hi, sess_lo, w1t_hi, w1t_lo, w2t_hi, w2t_lo);
    hipLaunchKernelGGL((mlp_gemm<512, 256, 0, 32>), dim3(NB / 32, 2), dim3(256), 0, stream,
                       sess_hi, sess_lo, w1t_hi, w1t_lo, b1, h_hi, h_lo, (float*)nullptr, (ushortT*)nullptr);
    hipLaunchKernelGGL((mlp_gemm<256, 512, 1, 64>), dim3(NB / 64, 4), dim3(256), 0, stream,
                       h_hi, h_lo, w2t_hi, w2t_lo, b2, (ushortT*)nullptr, (ushortT*)nullptr, proj, projb);
    hipLaunchKernelGGL(sim_mfma_kernel, dim3(NTRI), dim3(512), 0, stream,
                       (const short*)projb, pkeys);
    hipLaunchKernelGGL(rerank_out_kernel, dim3(NB / 4), dim3(256), 0, stream,
                       proj, pkeys, sess, out, cos_out);
}

// Round 18
// 133.008 us; speedup vs baseline: 1.1451x; 1.1451x over previous
//
#include <hip/hip_runtime.h>
#include <hip/hip_bf16.h>
#include <math.h>

#define NB 8192
#define DD 512
#define HH 256
#define TB 128             // sim tile 128x128
#define BK 32              // mlp gemm k-tile
#define BK2 64             // sim k-tile
#define KT2 (DD / BK2)     // 8 k-steps in sim
#define NSLOT 64
#define ROWKEYS (NSLOT * 3)
#define NCAND 6
#define NTRI 2080          // 64*65/2

typedef unsigned short ushortT;
typedef __attribute__((ext_vector_type(8))) short bf16x8;
typedef __attribute__((ext_vector_type(4))) float f32x4;

#define AS1(p) ((const __attribute__((address_space(1))) void*)(p))
#define AS3(p) ((__attribute__((address_space(3))) void*)(p))

__device__ __forceinline__ ushortT bf16rne(float f) {
    unsigned u = __float_as_uint(f);
    unsigned r = u + 0x7FFFu + ((u >> 16) & 1u);
    return (ushortT)(r >> 16);
}
__device__ __forceinline__ float bf16tof(ushortT h) {
    return __uint_as_float(((unsigned)h) << 16);
}

// ---------------- Kernel 0: prep ----------------
__global__ __launch_bounds__(256)
void prep_kernel(const float* __restrict__ sess, const float* __restrict__ W1,
                 const float* __restrict__ W2,
                 ushortT* __restrict__ sess_hi, ushortT* __restrict__ sess_lo,
                 ushortT* __restrict__ w1t_hi, ushortT* __restrict__ w1t_lo,
                 ushortT* __restrict__ w2t_hi, ushortT* __restrict__ w2t_lo) {
    const int b = blockIdx.x, t = threadIdx.x;
    if (b < 2048) {
        size_t i = (size_t)b * 2048 + t * 8;
        float4 f0 = *(const float4*)&sess[i];
        float4 f1 = *(const float4*)&sess[i + 4];
        float f[8] = {f0.x, f0.y, f0.z, f0.w, f1.x, f1.y, f1.z, f1.w};
        unsigned hp[4], lp[4];
#pragma unroll
        for (int j = 0; j < 4; ++j) {
            ushortT h0 = bf16rne(f[2 * j]), h1 = bf16rne(f[2 * j + 1]);
            ushortT l0 = bf16rne(f[2 * j] - bf16tof(h0));
            ushortT l1 = bf16rne(f[2 * j + 1] - bf16tof(h1));
            hp[j] = (unsigned)h0 | ((unsigned)h1 << 16);
            lp[j] = (unsigned)l0 | ((unsigned)l1 << 16);
        }
        *(uint4*)&sess_hi[i] = *(uint4*)hp;
        *(uint4*)&sess_lo[i] = *(uint4*)lp;
    } else if (b < 2112) {
        int o = (b - 2048) * 2048 + t * 8;
        int k = o >> 8, c = o & 255;
        float4 f0 = *(const float4*)&W1[(size_t)k * 256 + c];
        float4 f1 = *(const float4*)&W1[(size_t)k * 256 + c + 4];
        float f[8] = {f0.x, f0.y, f0.z, f0.w, f1.x, f1.y, f1.z, f1.w};
#pragma unroll
        for (int j = 0; j < 8; ++j) {
            ushortT h = bf16rne(f[j]);
            w1t_hi[(size_t)(c + j) * 512 + k] = h;
            w1t_lo[(size_t)(c + j) * 512 + k] = bf16rne(f[j] - bf16tof(h));
        }
    } else {
        int o = (b - 2112) * 2048 + t * 8;
        int k = o >> 9, c = o & 511;
        float4 f0 = *(const float4*)&W2[(size_t)k * 512 + c];
        float4 f1 = *(const float4*)&W2[(size_t)k * 512 + c + 4];
        float f[8] = {f0.x, f0.y, f0.z, f0.w, f1.x, f1.y, f1.z, f1.w};
#pragma unroll
        for (int j = 0; j < 8; ++j) {
            ushortT h = bf16rne(f[j]);
            w2t_hi[(size_t)(c + j) * 256 + k] = h;
            w2t_lo[(size_t)(c + j) * 256 + k] = bf16rne(f[j] - bf16tof(h));
        }
    }
}

// -------- Kernel 1/2: split-bf16 MFMA GEMM, C = A @ B^T (+bias), TM x 128 tile --------
// BN=128 -> LDS 40/48 KB -> 3-4 blocks/CU: inter-block TLP hides K-step latency.
template <int KDIM, int NOUT, int EPI, int TM>
__global__ __launch_bounds__(256)
void mlp_gemm(const ushortT* __restrict__ Ahi, const ushortT* __restrict__ Alo,
              const ushortT* __restrict__ Bhi, const ushortT* __restrict__ Blo,
              const float* __restrict__ bias,
              ushortT* __restrict__ Ohi, ushortT* __restrict__ Olo,
              float* __restrict__ Of, ushortT* __restrict__ Ob) {
    constexpr int AC = TM / 16;           // A 16-row chunks per matrix
    constexpr int BC = 8;                 // B 16-row chunks per matrix (BN=128)
    constexpr int CHUNKS = 2 * AC + 2 * BC;
    constexpr int QN = CHUNKS / 4;
    constexpr int BUFS = CHUNKS * 512;
    constexpr int MI = TM / 32;
    constexpr int NJ = 4;                 // 64 cols per wave-half
    __shared__ short gsmem[2 * BUFS];
    const int KTILES = KDIM / BK;
    const int t = threadIdx.x;
    const int w = t >> 6, l = t & 63;
    const int wr = w >> 1, wc = w & 1;
    const int tx = l & 15, tg = l >> 4;
    const int rb = blockIdx.x * TM;
    const int cb = blockIdx.y * 128;

    const int rin = l >> 2;
    const int tgs = (l & 3) ^ ((rin >> 1) & 3);
    const int loff = tx * BK + ((tg ^ ((tx >> 1) & 3)) << 3);

    f32x4 acc[MI][NJ];
#pragma unroll
    for (int i = 0; i < MI; ++i)
#pragma unroll
        for (int j = 0; j < NJ; ++j) acc[i][j] = (f32x4){0.f, 0.f, 0.f, 0.f};

#define GSTAGE(buf, k0v)                                                                     \
    {                                                                                        \
        _Pragma("unroll")                                                                    \
        for (int q = 0; q < QN; ++q) {                                                       \
            int c = w * QN + q;                                                              \
            const ushortT* src; int row; int lofs;                                           \
            if (c < AC)              { src = Ahi; row = rb + c * 16 + rin;                lofs = c * 512; } \
            else if (c < 2 * AC)     { src = Alo; row = rb + (c - AC) * 16 + rin;         lofs = c * 512; } \
            else if (c < 2 * AC + BC){ src = Bhi; row = cb + (c - 2 * AC) * 16 + rin;     lofs = c * 512; } \
            else                     { src = Blo; row = cb + (c - 2 * AC - BC) * 16 + rin; lofs = c * 512; } \
            const ushortT* g = src + (size_t)row * KDIM + (k0v) + tgs * 8;                   \
            __builtin_amdgcn_global_load_lds(AS1(g), AS3(gsmem + (buf) * BUFS + lofs + l * 8), 16, 0, 0); \
        }                                                                                    \
    }

#define GCOMPUTE(kt)                                                                         \
    {                                                                                        \
        const short* Bu = gsmem + ((kt) & 1) * BUFS;                                         \
        bf16x8 ah[MI], al[MI], bh[NJ], bl[NJ];                                               \
        _Pragma("unroll")                                                                    \
        for (int mi = 0; mi < MI; ++mi) {                                                    \
            ah[mi] = *(const bf16x8*)&Bu[(wr * MI + mi) * 512 + loff];                       \
            al[mi] = *(const bf16x8*)&Bu[AC * 512 + (wr * MI + mi) * 512 + loff];            \
        }                                                                                    \
        _Pragma("unroll")                                                                    \
        for (int nj = 0; nj < NJ; ++nj) {                                                    \
            bh[nj] = *(const bf16x8*)&Bu[2 * AC * 512 + (wc * NJ + nj) * 512 + loff];        \
            bl[nj] = *(const bf16x8*)&Bu[(2 * AC + BC) * 512 + (wc * NJ + nj) * 512 + loff]; \
        }                                                                                    \
        asm volatile("s_waitcnt lgkmcnt(0)" ::: "memory");                                   \
        __builtin_amdgcn_sched_barrier(0);                                                   \
        __builtin_amdgcn_s_barrier();                                                        \
        __builtin_amdgcn_sched_barrier(0);                                                   \
        _Pragma("unroll")                                                                    \
        for (int mi = 0; mi < MI; ++mi)                                                      \
            _Pragma("unroll")                                                                \
            for (int nj = 0; nj < NJ; ++nj) {                                                \
                acc[mi][nj] = __builtin_amdgcn_mfma_f32_16x16x32_bf16(ah[mi], bh[nj], acc[mi][nj], 0, 0, 0); \
                acc[mi][nj] = __builtin_amdgcn_mfma_f32_16x16x32_bf16(ah[mi], bl[nj], acc[mi][nj], 0, 0, 0); \
                acc[mi][nj] = __builtin_amdgcn_mfma_f32_16x16x32_bf16(al[mi], bh[nj], acc[mi][nj], 0, 0, 0); \
            }                                                                                \
    }

    GSTAGE(0, 0);
    for (int kt = 0; kt < KTILES - 1; ++kt) {
        GSTAGE((kt + 1) & 1, (kt + 1) * BK);
        if constexpr (TM == 64) { asm volatile("s_waitcnt vmcnt(6)" ::: "memory"); }
        else                    { asm volatile("s_waitcnt vmcnt(5)" ::: "memory"); }
        __builtin_amdgcn_sched_barrier(0);
        __builtin_amdgcn_s_barrier();
        __builtin_amdgcn_sched_barrier(0);
        GCOMPUTE(kt);
    }
    asm volatile("s_waitcnt vmcnt(0)" ::: "memory");
    __builtin_amdgcn_sched_barrier(0);
    __builtin_amdgcn_s_barrier();
    __builtin_amdgcn_sched_barrier(0);
    GCOMPUTE(KTILES - 1);
#undef GSTAGE
#undef GCOMPUTE

#pragma unroll
    for (int mi = 0; mi < MI; ++mi) {
#pragma unroll
        for (int nj = 0; nj < NJ; ++nj) {
            int col = cb + wc * 64 + nj * 16 + tx;
            float bv = bias[col];
#pragma unroll
            for (int rr = 0; rr < 4; ++rr) {
                int row = rb + wr * (TM / 2) + mi * 16 + tg * 4 + rr;
                float v = acc[mi][nj][rr] + bv;
                if (EPI == 0) {
                    v = fmaxf(v, 0.f);
                    ushortT h = bf16rne(v);
                    Ohi[(size_t)row * NOUT + col] = h;
                    Olo[(size_t)row * NOUT + col] = bf16rne(v - bf16tof(h));
                } else {
                    Of[(size_t)row * NOUT + col] = v;
                    Ob[(size_t)row * NOUT + col] = bf16rne(v);
                }
            }
        }
    }
}

// ---- packed-key top-3 helpers (keys unique: index embedded -> any exact network OK) ----
__device__ __forceinline__ unsigned umaxu(unsigned a, unsigned b) { return a > b ? a : b; }
__device__ __forceinline__ unsigned uminu(unsigned a, unsigned b) { return a < b ? a : b; }
__device__ __forceinline__ void merge3k(unsigned& a0, unsigned& a1, unsigned& a2,
                                        unsigned b0, unsigned b1, unsigned b2) {
    unsigned m0 = a0 > b0 ? a0 : b0;
    bool c0 = a0 > b0;
    unsigned ca1 = c0 ? a1 : b1;
    unsigned cb0 = c0 ? b0 : a0;
    unsigned ca2 = c0 ? a2 : b2;
    unsigned cb1 = c0 ? b1 : a1;
    bool c1 = ca1 > cb0;
    unsigned m1 = c1 ? ca1 : cb0;
    unsigned x = c1 ? ca2 : ca1;
    unsigned y = c1 ? cb0 : cb1;
    unsigned m2 = x > y ? x : y;
    a0 = m0; a1 = m1; a2 = m2;
}
// exact top-3 of 4 distinct keys
__device__ __forceinline__ void top3of4(unsigned a, unsigned b, unsigned c, unsigned d,
                                        unsigned& k0, unsigned& k1, unsigned& k2) {
    unsigned s1 = umaxu(a, b), t1 = uminu(a, b);
    unsigned s2 = umaxu(c, d), t2 = uminu(c, d);
    bool cw = s1 > s2;
    unsigned c2 = cw ? s2 : s1;
    unsigned tw = cw ? t1 : t2;
    unsigned tl = cw ? t2 : t1;
    k0 = cw ? s1 : s2;
    k1 = umaxu(c2, tw);
    k2 = umaxu(uminu(c2, tw), tl);
}
__device__ __forceinline__ unsigned packkey(float f, unsigned idx) {
    unsigned u = __float_as_uint(f);
    unsigned tt = (unsigned)((int)u >> 31) | 0x80000000u;
    return ((u ^ tt) & 0xFFFFE000u) | (8191u - idx);
}

// ------- Kernel 3: symmetric bf16 MFMA sim, 128x128 tiles, BK=64, XCD-chunked triangle -------
// Best-measured configuration (R15/R16): 4 waves, 64 KB LDS dbuf, cheap exact select networks.
__global__ __launch_bounds__(256)
void sim_mfma_kernel(const short* __restrict__ projb, unsigned* __restrict__ pkeys) {
    const int b = blockIdx.x;
    const int L = (b & 7) * 260 + (b >> 3);
    int jbk = (int)((sqrtf(8.0f * L + 1.0f) - 1.0f) * 0.5f);
    while ((jbk + 1) * (jbk + 2) / 2 <= L) ++jbk;
    while (jbk * (jbk + 1) / 2 > L) --jbk;
    const int ib = L - jbk * (jbk + 1) / 2;
    const bool do_tr = (ib < jbk);

    __shared__ short smem[2 * TB * BK2 * 2];   // 64 KB: As[2][128*64], Bs[2][128*64]
    short* As = smem;
    short* Bs = smem + 2 * TB * BK2;
    unsigned* evu = (unsigned*)smem;           // epilogue overlay [128][25]
    unsigned* evt = (unsigned*)smem + 3200;    // transposed overlay [128][6]

    const int t = threadIdx.x;
    const int w = t >> 6, l = t & 63;
    const int wr = w >> 1, wc = w & 1;
    const int tx = l & 15, tg = l >> 4;
    const int rb = ib * TB;
    const int jb = jbk * TB;

    const int sl8 = (((l & 7) ^ (l >> 3)) << 3);
    const int sw0 = (((0 + tg) ^ (tx & 7)) << 3);
    const int sw1 = (((4 + tg) ^ (tx & 7)) << 3);

    f32x4 acc[4][4];
#pragma unroll
    for (int i = 0; i < 4; ++i)
#pragma unroll
        for (int j = 0; j < 4; ++j) acc[i][j] = (f32x4){0.f, 0.f, 0.f, 0.f};

#define STAGE(buf, k0)                                                                      \
    {                                                                                       \
        _Pragma("unroll")                                                                   \
        for (int q = 0; q < 4; ++q) {                                                       \
            int c = w * 4 + q;                                                              \
            const short* ga = projb + (size_t)(rb + c * 8 + (l >> 3)) * DD + (k0) + sl8;    \
            __builtin_amdgcn_global_load_lds(AS1(ga), AS3(As + (buf) * 8192 + c * 512 + l * 8), 16, 0, 0); \
            const short* gb = projb + (size_t)(jb + c * 8 + (l >> 3)) * DD + (k0) + sl8;    \
            __builtin_amdgcn_global_load_lds(AS1(gb), AS3(Bs + (buf) * 8192 + c * 512 + l * 8), 16, 0, 0); \
        }                                                                                   \
    }

#define COMPUTE(kt)                                                                          \
    {                                                                                        \
        const short* Ab = As + ((kt) & 1) * 8192;                                            \
        const short* Bb = Bs + ((kt) & 1) * 8192;                                            \
        bf16x8 af0[4], af1[4], bf0[4], bf1[4];                                               \
        _Pragma("unroll")                                                                    \
        for (int mi = 0; mi < 4; ++mi) {                                                     \
            int row = wr * 64 + mi * 16 + tx;                                                \
            af0[mi] = *(const bf16x8*)&Ab[row * 64 + sw0];                                   \
            af1[mi] = *(const bf16x8*)&Ab[row * 64 + sw1];                                   \
        }                                                                                    \
        _Pragma("unroll")                                                                    \
        for (int nj = 0; nj < 4; ++nj) {                                                     \
            int row = wc * 64 + nj * 16 + tx;                                                \
            bf0[nj] = *(const bf16x8*)&Bb[row * 64 + sw0];                                   \
            bf1[nj] = *(const bf16x8*)&Bb[row * 64 + sw1];                                   \
        }                                                                                    \
        asm volatile("s_waitcnt lgkmcnt(0)" ::: "memory");                                   \
        __builtin_amdgcn_sched_barrier(0);                                                   \
        __builtin_amdgcn_s_barrier();                                                        \
        __builtin_amdgcn_sched_barrier(0);                                                   \
        _Pragma("unroll")                                                                    \
        for (int mi = 0; mi < 4; ++mi)                                                       \
            _Pragma("unroll")                                                                \
            for (int nj = 0; nj < 4; ++nj)                                                   \
                acc[mi][nj] = __builtin_amdgcn_mfma_f32_16x16x32_bf16(af0[mi], bf0[nj], acc[mi][nj], 0, 0, 0); \
        _Pragma("unroll")                                                                    \
        for (int mi = 0; mi < 4; ++mi)                                                       \
            _Pragma("unroll")                                                                \
            for (int nj = 0; nj < 4; ++nj)                                                   \
                acc[mi][nj] = __builtin_amdgcn_mfma_f32_16x16x32_bf16(af1[mi], bf1[nj], acc[mi][nj], 0, 0, 0); \
    }

    STAGE(0, 0);
    for (int kt = 0; kt < KT2 - 1; ++kt) {
        STAGE((kt + 1) & 1, (kt + 1) * BK2);
        asm volatile("s_waitcnt vmcnt(8)" ::: "memory");
        __builtin_amdgcn_sched_barrier(0);
        __builtin_amdgcn_s_barrier();
        __builtin_amdgcn_sched_barrier(0);
        COMPUTE(kt);
    }
    asm volatile("s_waitcnt vmcnt(0)" ::: "memory");
    __builtin_amdgcn_sched_barrier(0);
    __builtin_amdgcn_s_barrier();
    __builtin_amdgcn_sched_barrier(0);
    COMPUTE(KT2 - 1);
#undef STAGE
#undef COMPUTE

    __syncthreads();   // K-loop done everywhere before LDS overlay

    // ---- direct epilogue: per-row top3 over this block's 128 cols ----
    unsigned cinv[4];
#pragma unroll
    for (int nj = 0; nj < 4; ++nj)
        cinv[nj] = 8191u - (unsigned)(jb + wc * 64 + nj * 16 + tx);
#pragma unroll
    for (int mi = 0; mi < 4; ++mi) {
#pragma unroll
        for (int rr = 0; rr < 4; ++rr) {
            unsigned kk[4];
#pragma unroll
            for (int nj = 0; nj < 4; ++nj) {
                unsigned u = __float_as_uint(acc[mi][nj][rr]);
                unsigned tt = (unsigned)((int)u >> 31) | 0x80000000u;
                kk[nj] = ((u ^ tt) & 0xFFFFE000u) | cinv[nj];
            }
            unsigned k0, k1, k2;
            top3of4(kk[0], kk[1], kk[2], kk[3], k0, k1, k2);
#pragma unroll
            for (int s = 1; s <= 2; s <<= 1) {
                unsigned b0 = (unsigned)__shfl_xor((int)k0, s, 64);
                unsigned b1 = (unsigned)__shfl_xor((int)k1, s, 64);
                unsigned b2 = (unsigned)__shfl_xor((int)k2, s, 64);
                merge3k(k0, k1, k2, b0, b1, b2);
            }
            if ((tx & 3) == 0) {
                int lrow = wr * 64 + mi * 16 + tg * 4 + rr;
                unsigned* e = &evu[lrow * 25 + (wc * 4 + (tx >> 2)) * 3];
                e[0] = k0; e[1] = k1; e[2] = k2;
            }
        }
    }

    // ---- transposed epilogue (strictly-upper): per-col top3 over this block's 128 rows ----
    if (do_tr) {
#pragma unroll
        for (int nj = 0; nj < 4; ++nj) {
            unsigned v[16];
#pragma unroll
            for (int mi = 0; mi < 4; ++mi)
#pragma unroll
                for (int rr = 0; rr < 4; ++rr) {
                    unsigned idx = (unsigned)(rb + wr * 64 + mi * 16 + tg * 4 + rr);
                    v[mi * 4 + rr] = packkey(acc[mi][nj][rr], idx);
                }
            unsigned x0, x1, x2, y0, y1, y2, z0, z1, z2;
            top3of4(v[0], v[1], v[2], v[3], x0, x1, x2);
            top3of4(v[4], v[5], v[6], v[7], y0, y1, y2);
            merge3k(x0, x1, x2, y0, y1, y2);
            top3of4(v[8], v[9], v[10], v[11], y0, y1, y2);
            top3of4(v[12], v[13], v[14], v[15], z0, z1, z2);
            merge3k(y0, y1, y2, z0, z1, z2);
            merge3k(x0, x1, x2, y0, y1, y2);
#pragma unroll
            for (int s = 16; s <= 32; s <<= 1) {
                unsigned b0 = (unsigned)__shfl_xor((int)x0, s, 64);
                unsigned b1 = (unsigned)__shfl_xor((int)x1, s, 64);
                unsigned b2 = (unsigned)__shfl_xor((int)x2, s, 64);
                merge3k(x0, x1, x2, b0, b1, b2);
            }
            if (tg == 0) {
                int col = wc * 64 + nj * 16 + tx;
                unsigned* e = &evt[col * 6 + wr * 3];
                e[0] = x0; e[1] = x1; e[2] = x2;
            }
        }
    }
    __syncthreads();

    if (t < TB) {
        const unsigned* e = &evu[t * 25];
        unsigned k0 = e[0], k1 = e[1], k2 = e[2];
#pragma unroll
        for (int s = 1; s < 8; ++s) merge3k(k0, k1, k2, e[s * 3], e[s * 3 + 1], e[s * 3 + 2]);
        unsigned* pk = pkeys + (size_t)(rb + t) * ROWKEYS + jbk * 3;
        pk[0] = k0; pk[1] = k1; pk[2] = k2;
    }
    if (do_tr && t < TB) {
        const unsigned* e = &evt[t * 6];
        unsigned k0 = e[0], k1 = e[1], k2 = e[2];
        merge3k(k0, k1, k2, e[3], e[4], e[5]);
        unsigned* pk = pkeys + (size_t)(jb + t) * ROWKEYS + ib * 3;
        pk[0] = k0; pk[1] = k1; pk[2] = k2;
    }
}

// --- Kernel 4: parallel top-6 of 192 keys + exact fp64 re-rank + softmax + gather + out ---
__global__ __launch_bounds__(256)
void rerank_out_kernel(const float* __restrict__ proj, const unsigned* __restrict__ pkeys,
                       const float* __restrict__ sess, float* __restrict__ out,
                       float* __restrict__ cos_out) {
    int r = blockIdx.x * 4 + (threadIdx.x >> 6);
    int t = threadIdx.x & 63;
    const unsigned* pk = pkeys + (size_t)r * ROWKEYS;
    unsigned a0 = pk[3 * t], a1 = pk[3 * t + 1], a2 = pk[3 * t + 2];
    {
        unsigned m01 = a0 > a1 ? a0 : a1, n01 = a0 > a1 ? a1 : a0;
        unsigned m2 = n01 > a2 ? n01 : a2, n2 = n01 > a2 ? a2 : n01;
        a0 = m01 > m2 ? m01 : m2;
        a1 = m01 > m2 ? m2 : m01;
        a2 = n2;
    }
    unsigned ck[NCAND];
#pragma unroll
    for (int i = 0; i < NCAND; ++i) {
        unsigned m = a0;
#pragma unroll
        for (int s = 1; s < 64; s <<= 1) {
            unsigned o = (unsigned)__shfl_xor((int)m, s, 64);
            m = m > o ? m : o;
        }
        ck[i] = m;
        if (a0 == m) { a0 = a1; a1 = a2; a2 = 0; }
    }
    int cj[NCAND];
#pragma unroll
    for (int i = 0; i < NCAND; ++i) cj[i] = 8191 - (int)(ck[i] & 0x1FFFu);

    const float* pr = proj + (size_t)r * DD;
    float myp[8];
#pragma unroll
    for (int k = 0; k < 8; ++k) myp[k] = pr[t * 8 + k];
    double part[NCAND];
#pragma unroll
    for (int i = 0; i < NCAND; ++i) {
        const float* pc = proj + (size_t)cj[i] * DD;
        double s = 0.0;
#pragma unroll
        for (int k = 0; k < 8; ++k) s += (double)myp[k] * (double)pc[t * 8 + k];
        part[i] = s;
    }
#pragma unroll
    for (int i = 0; i < NCAND; ++i) {
#pragma unroll
        for (int s = 1; s < 64; s <<= 1) part[i] += __shfl_xor(part[i], s, 64);
    }
    double bv0 = -1e300, bv1 = -1e300, bv2 = -1e300;
    int bj0 = 0x7fffffff, bj1 = 0x7fffffff, bj2 = 0x7fffffff;
#pragma unroll
    for (int i = 0; i < NCAND; ++i) {
        double v = part[i]; int j = cj[i];
        bool g2 = (v > bv2) || (v == bv2 && j < bj2);
        bool g1 = (v > bv1) || (v == bv1 && j < bj1);
        bool g0 = (v > bv0) || (v == bv0 && j < bj0);
        if (g2) {
            if (g1) {
                if (g0) { bv2 = bv1; bj2 = bj1; bv1 = bv0; bj1 = bj0; bv0 = v; bj0 = j; }
                else    { bv2 = bv1; bj2 = bj1; bv1 = v; bj1 = j; }
            } else      { bv2 = v; bj2 = j; }
        }
    }
    double e1 = exp(bv1 - bv0), e2 = exp(bv2 - bv0);
    double inv = 1.0 / (1.0 + e1 + e2);
    float w0 = (float)inv, w1 = (float)(e1 * inv), w2 = (float)(e2 * inv);
    if (t == 0) {
        cos_out[r * 3 + 0] = w0; cos_out[r * 3 + 1] = w1; cos_out[r * 3 + 2] = w2;
    }
    const float4* s0 = (const float4*)(sess + (size_t)bj0 * DD);
    const float4* s1 = (const float4*)(sess + (size_t)bj1 * DD);
    const float4* s2 = (const float4*)(sess + (size_t)bj2 * DD);
    float4* o = (float4*)(out + (size_t)r * 3 * DD);
    float4* nb = (float4*)(out + (size_t)NB * 3 * DD + (size_t)r * DD);
#pragma unroll
    for (int e = 0; e < 2; ++e) {
        int q = t + e * 64;
        float4 x0 = s0[q], x1 = s1[q], x2 = s2[q];
        o[q] = x0; o[128 + q] = x1; o[256 + q] = x2;
        float4 v;
        v.x = fmaf(w0, x0.x, fmaf(w1, x1.x, w2 * x2.x));
        v.y = fmaf(w0, x0.y, fmaf(w1, x1.y, w2 * x2.y));
        v.z = fmaf(w0, x0.z, fmaf(w1, x1.z, w2 * x2.z));
        v.w = fmaf(w0, x0.w, fmaf(w1, x1.w, w2 * x2.w));
        nb[q] = v;
    }
}

extern "C" void kernel_launch(void* const* d_in, const int* in_sizes, int n_in,
                              void* d_out, int out_size, void* d_ws, size_t ws_size,
                              hipStream_t stream) {
    const float* sess = (const float*)d_in[0];
    // d_in[1] = pool_emb: unused by the reference
    const float* W1 = (const float*)d_in[2];
    const float* b1 = (const float*)d_in[3];
    const float* W2 = (const float*)d_in[4];
    const float* b2 = (const float*)d_in[5];
    float* out = (float*)d_out;

    const size_t MBc = 1u << 20;
    char* W = (char*)d_ws;
    float*   proj    = (float*)W;
    ushortT* sess_hi = (ushortT*)W;
    ushortT* sess_lo = sess_hi + (size_t)NB * DD;
    ushortT* projb   = (ushortT*)(W + 16 * MBc);
    ushortT* h_hi    = (ushortT*)(W + 24 * MBc);
    ushortT* h_lo    = (ushortT*)(W + 28 * MBc);
    ushortT* w1t_hi  = (ushortT*)(W + 32 * MBc);
    ushortT* w1t_lo  = w1t_hi + 256 * 512;
    ushortT* w2t_hi  = w1t_lo + 256 * 512;
    ushortT* w2t_lo  = w2t_hi + 512 * 256;
    unsigned* pkeys  = (unsigned*)(W + 24 * MBc);   // overlays h_hi/h_lo after gemm2

    float* cos_out = out + (size_t)NB * 3 * DD + (size_t)NB * DD;

    hipLaunchKernelGGL(prep_kernel, dim3(2176), dim3(256), 0, stream,
                       sess, W1, W2, sess_hi, sess_lo, w1t_hi, w1t_lo, w2t_hi, w2t_lo);
    hipLaunchKernelGGL((mlp_gemm<512, 256, 0, 32>), dim3(NB / 32, 2), dim3(256), 0, stream,
                       sess_hi, sess_lo, w1t_hi, w1t_lo, b1, h_hi, h_lo, (float*)nullptr, (ushortT*)nullptr);
    hipLaunchKernelGGL((mlp_gemm<256, 512, 1, 64>), dim3(NB / 64, 4), dim3(256), 0, stream,
                       h_hi, h_lo, w2t_hi, w2t_lo, b2, (ushortT*)nullptr, (ushortT*)nullptr, proj, projb);
    hipLaunchKernelGGL(sim_mfma_kernel, dim3(NTRI), dim3(256), 0, stream,
                       (const short*)projb, pkeys);
    hipLaunchKernelGGL(rerank_out_kernel, dim3(NB / 4), dim3(256), 0, stream,
                       proj, pkeys, sess, out, cos_out);
}